// Round 9
// baseline (110.580 us; speedup 1.0000x reference)
//
#include <hip/hip_runtime.h>
#include <hip/hip_bf16.h>
#include <math.h>

#define B_    8
#define C_    256
#define L_    4096
#define OCH_  256

typedef __attribute__((ext_vector_type(8)))  short bf16x8;
typedef __attribute__((ext_vector_type(16))) float f32x16;
typedef __attribute__((ext_vector_type(4)))  int   i32x4;

static __device__ __forceinline__ unsigned short bf16_rne(float f) {
    unsigned u = __float_as_uint(f);
    unsigned r = u + 0x7FFFu + ((u >> 16) & 1u);
    return (unsigned short)(r >> 16);
}

static __device__ __forceinline__ void gload_lds16(const void* g, void* l) {
    __builtin_amdgcn_global_load_lds(
        (const __attribute__((address_space(1))) unsigned int*)g,
        (__attribute__((address_space(3))) unsigned int*)l, 16, 0, 0);
}

// ---------------------------------------------------------------------------
// K0: pack W[o][c][k] -> Wpk[o][gran][0..7]=hi, [8..15]=lo
//     gran = k*32 + c/8 (96 granules of 8 consecutive c, k-major), e = c&7.
// ---------------------------------------------------------------------------
__global__ void k_split(const float* __restrict__ W,
                        unsigned short* __restrict__ Wpk) {
    int i = blockIdx.x * 256 + threadIdx.x;          // o*768 + c*3 + k
    if (i >= OCH_ * C_ * 3) return;
    int k = i % 3;
    int c = (i / 3) & 255;
    int o = i / 768;
    float w = W[i];
    unsigned short hb = bf16_rne(w);
    float hi = __uint_as_float((unsigned)hb << 16);
    unsigned short lb = bf16_rne(w - hi);
    int base = o * 1536 + (k * 32 + (c >> 3)) * 16 + (c & 7);
    Wpk[base]     = hb;
    Wpk[base + 8] = lb;
}

// ---------------------------------------------------------------------------
// K1: offset network, c-loop split across 2 wave-groups (32 loads/thread).
// Block 512 thr: (l, g, half). Partial h combined via LDS; half 0 finishes
// layer 2; wave 0 does softmax and emits window-form coef:
//   coef[(b*3+t)*L + l] = { d0, d1, bits(i0f2), 0 }
// ---------------------------------------------------------------------------
__global__ __launch_bounds__(512) void k_offsets(
        const float* __restrict__ x,
        const float* __restrict__ w1, const float* __restrict__ b1,
        const float* __restrict__ w2, const float* __restrict__ b2,
        float4* __restrict__ coef) {
    __shared__ float sH[2][4][16][65];               // 33.3 KB [half][g][o][l]
    __shared__ float sOm[64][37];                    // 9.25 KB
    int tid  = threadIdx.x;
    int l    = tid & 63;
    int g    = (tid >> 6) & 3;
    int half = tid >> 8;
    int blk  = blockIdx.x;
    int b    = blk & 7;                              // XCD affinity
    int l0   = (blk >> 3) << 6;
    int lg   = l0 + l;

    const float* xg = x + (size_t)b * C_ * L_ + (size_t)(g * 64 + half * 32) * L_ + lg;

    float h[16];
    #pragma unroll
    for (int o = 0; o < 16; ++o) h[o] = half ? 0.0f : b1[g * 16 + o];
    #pragma unroll 4
    for (int cg = 0; cg < 32; ++cg) {
        float xv = xg[(size_t)cg * L_];
        const float* w1p = w1 + (g * 16) * 64 + half * 32 + cg;
        #pragma unroll
        for (int o = 0; o < 16; ++o) h[o] = fmaf(xv, w1p[o * 64], h[o]);
    }
    #pragma unroll
    for (int o = 0; o < 16; ++o) sH[half][g][o][l] = h[o];
    __syncthreads();

    if (half == 0) {
        float om9[9];
        #pragma unroll
        for (int j = 0; j < 9; ++j) om9[j] = b2[g * 9 + j];
        #pragma unroll
        for (int o = 0; o < 16; ++o) {
            float a  = h[o] + sH[1][g][o][l];
            float hv = 0.5f * a * (1.0f + erff(a * 0.70710678118654752f));
            const float* w2p = w2 + g * 144 + o;     // w2[g][j][o]
            #pragma unroll
            for (int j = 0; j < 9; ++j) om9[j] = fmaf(hv, w2p[j * 16], om9[j]);
        }
        #pragma unroll
        for (int j = 0; j < 9; ++j) sOm[l][g * 9 + j] = om9[j];
    }
    __syncthreads();
    if (tid >= 64) return;

    float om[36];
    #pragma unroll
    for (int j = 0; j < 36; ++j) om[j] = sOm[tid][j];
    om[1] = 0.0f; om[3] = 0.0f; om[5] = 0.0f;
    float m = om[3];
    #pragma unroll
    for (int j = 4; j < 36; ++j) m = fmaxf(m, om[j]);
    float ssum = 0.0f;
    #pragma unroll
    for (int j = 3; j < 36; ++j) ssum += expf(om[j] - m);
    float inv = 1.0f / ssum;

    int lpos = l0 + tid;
    float base = -1.0f + 2.0f * (float)lpos / (float)(L_ - 1);
    #pragma unroll
    for (int t = 0; t < 3; ++t) {
        float mod  = expf(om[3 + t] - m) * inv;
        float off  = om[2 * t] * (2.0f / (float)L_);
        float grid = base + (-0.5f + 0.5f * (float)t) + off;
        float pp   = (grid + 1.0f) * 0.5f * (float)(L_ - 1);
        float fp   = floorf(pp);
        int i0 = (int)fp, i1 = i0 + 1;
        float w = pp - fp;
        float c0 = (i0 >= 0 && i0 < L_) ? (1.0f - w) * mod : 0.0f;
        float c1 = (i1 >= 0 && i1 < L_) ? w * mod : 0.0f;
        int i0c  = min(max(i0, 0), L_ - 1);
        int i1c  = min(max(i1, 0), L_ - 1);
        int i0f2 = min(max(i0, 0), L_ - 2);
        float d0 = (i0c == i0f2     ? c0 : 0.0f) + (i1c == i0f2     ? c1 : 0.0f);
        float d1 = (i0c == i0f2 + 1 ? c0 : 0.0f) + (i1c == i0f2 + 1 ? c1 : 0.0f);
        coef[((size_t)b * 3 + t) * L_ + lpos] =
            make_float4(d0, d1, __int_as_float(i0f2), 0.0f);
    }
}

// ---------------------------------------------------------------------------
// K2: materialize sampled matrix S, GEMM-blocked:
//   S[b][lt][s][l] : i32x4 = 8 bf16 for kk in [8s,8s+8), l-tile of 64.
// Thread handles 2 granules (s, s+48): 2 independent gather streams (ILP).
// ---------------------------------------------------------------------------
__global__ __launch_bounds__(256) void k_sample(
        const float* __restrict__ x, const float4* __restrict__ coef,
        i32x4* __restrict__ Sg) {
    int tid  = threadIdx.x;
    int l    = tid & 63;
    int unit = tid >> 6;                             // 0..3
    int bid  = blockIdx.x;
    int b    = bid & 7;                              // XCD affinity
    int r    = bid >> 3;
    int lt   = r & 63;
    int sg   = r >> 6;                               // 0..11
    int lgl  = lt * 64 + l;
    const float* xb = x + (size_t)b * C_ * L_;

    #pragma unroll
    for (int rep = 0; rep < 2; ++rep) {
        int s   = sg * 4 + unit + rep * 48;          // 0..95
        int tap = s >> 5;
        int c0  = s * 8 - tap * 256;
        float4 cf = coef[((size_t)b * 3 + tap) * L_ + lgl];
        float d0 = cf.x, d1 = cf.y;
        const float* xp = xb + (size_t)c0 * L_ + __float_as_int(cf.z);
        union { unsigned short us[8]; i32x4 v; } pk;
        #pragma unroll
        for (int e = 0; e < 8; ++e) {
            float g0 = xp[0], g1 = xp[1];
            pk.us[e] = bf16_rne(fmaf(g1, d1, g0 * d0));
            xp += L_;
        }
        Sg[((size_t)(b * 64 + lt) * 96 + s) * 64 + l] = pk.v;
    }
}

// ---------------------------------------------------------------------------
// K3: 2-pass split-precision MFMA GEMM, TRIPLE-buffered counted-vmcnt pipe.
// Block 512 thr (8 waves) -> 256o x 64l; wave wv owns o-rows wv*32..+32.
// Per chunk: batch ALL 16 A-loads + issue 2 gload_lds(ch+1 -> (ch+1)%3) ->
// s_waitcnt vmcnt(2) -> s_barrier -> 32 MFMAs (all operands resident).
// 3 LDS buffers + max-1-barrier wave skew => prefetch target (ch+1)%3 can
// never collide with a buffer still being read ((ch-1)%3 or ch%3).
// ---------------------------------------------------------------------------
__global__ __launch_bounds__(512, 4) void k_gemm(
        const unsigned short* __restrict__ Wpk,
        const float* __restrict__ bias,
        const i32x4* __restrict__ Sg,
        float* __restrict__ out) {
    __shared__ i32x4 sS[3][1024];                    // 48 KB

    const int tid  = threadIdx.x;
    const int lane = tid & 63;
    const int wv   = tid >> 6;                       // 0..7
    const int blk  = blockIdx.x;
    const int b    = blk & 7;                        // XCD affinity
    const int lt   = blk >> 3;
    const int l0   = lt * 64;
    const int q    = lane >> 5;
    const int l31  = lane & 31;

    const i32x4* Sblk = Sg + (size_t)(b * 64 + lt) * (96 * 64);
    const unsigned short* WA = Wpk + (size_t)(wv * 32 + l31) * 1536;

    f32x16 acc0, acc1;
    #pragma unroll
    for (int i = 0; i < 16; ++i) { acc0[i] = 0.f; acc1[i] = 0.f; }

    // prologue: stage chunk 0 into buffer 0
    gload_lds16(Sblk + tid,       &sS[0][tid]);
    gload_lds16(Sblk + 512 + tid, &sS[0][512 + tid]);

    #pragma unroll
    for (int ch = 0; ch < 6; ++ch) {
        const int br = ch % 3;
        const unsigned short* wc = WA + ch * 256 + q * 16;   // granule base

        // batch all A-loads for this chunk (8 granule pairs, hi+lo)
        bf16x8 ah[8], al[8];
        #pragma unroll
        for (int j = 0; j < 8; ++j) {
            ah[j] = *(const bf16x8*)(wc + j * 32);
            al[j] = *(const bf16x8*)(wc + j * 32 + 8);
        }

        if (ch < 5) {                                // S prefetch for ch+1
            const int bw = (ch + 1) % 3;
            const i32x4* src = Sblk + (ch + 1) * 1024;
            gload_lds16(src + tid,       &sS[bw][tid]);
            gload_lds16(src + 512 + tid, &sS[bw][512 + tid]);
            asm volatile("s_waitcnt vmcnt(2)" ::: "memory");  // S(ch)+A done
        } else {
            asm volatile("s_waitcnt vmcnt(0)" ::: "memory");
        }
        __builtin_amdgcn_sched_barrier(0);
        __builtin_amdgcn_s_barrier();                // prefetch stays in flight
        __builtin_amdgcn_sched_barrier(0);

        #pragma unroll
        for (int ks = 0; ks < 8; ++ks) {
            const i32x4* bp = &sS[br][(ks * 2 + q) * 64 + l31];
            bf16x8 bh0 = *(const bf16x8*)bp;
            bf16x8 bh1 = *(const bf16x8*)(bp + 32);
            __builtin_amdgcn_s_setprio(1);
            acc0 = __builtin_amdgcn_mfma_f32_32x32x16_bf16(ah[ks], bh0, acc0, 0, 0, 0);
            acc1 = __builtin_amdgcn_mfma_f32_32x32x16_bf16(ah[ks], bh1, acc1, 0, 0, 0);
            acc0 = __builtin_amdgcn_mfma_f32_32x32x16_bf16(al[ks], bh0, acc0, 0, 0, 0);
            acc1 = __builtin_amdgcn_mfma_f32_32x32x16_bf16(al[ks], bh1, acc1, 0, 0, 0);
            __builtin_amdgcn_s_setprio(0);
        }
    }

    // epilogue: bias + store. D: col=lane&31, row=(reg&3)+8*(reg>>2)+4*q
    #pragma unroll
    for (int reg = 0; reg < 16; ++reg) {
        int rr = (reg & 3) + 8 * (reg >> 2) + 4 * q;
        int o  = wv * 32 + rr;
        float bv = bias[o];
        float* op = out + ((size_t)b * 256 + o) * L_ + l0 + l31;
        op[0]  = acc0[reg] + bv;
        op[32] = acc1[reg] + bv;
    }
}

// ---------------------------------------------------------------------------
extern "C" void kernel_launch(void* const* d_in, const int* in_sizes, int n_in,
                              void* d_out, int out_size, void* d_ws, size_t ws_size,
                              hipStream_t stream) {
    const float* x      = (const float*)d_in[0];
    const float* weight = (const float*)d_in[1];
    const float* bias   = (const float*)d_in[2];
    const float* w1     = (const float*)d_in[3];
    const float* b1     = (const float*)d_in[4];
    const float* w2     = (const float*)d_in[5];
    const float* b2     = (const float*)d_in[6];
    float* out = (float*)d_out;

    const size_t COEF_B = (size_t)B_ * 3 * L_ * sizeof(float4);   // 1.5 MB
    const size_t W_B    = (size_t)OCH_ * 1536 * 2;                // 768 KB
    char* ws = (char*)d_ws;
    float4*         coef = (float4*)ws;
    unsigned short* Wpk  = (unsigned short*)(ws + COEF_B);
    i32x4*          Sg   = (i32x4*)(ws + COEF_B + W_B);           // 48 MB

    k_split<<<(OCH_ * C_ * 3 + 255) / 256, 256, 0, stream>>>(weight, Wpk);
    k_offsets<<<B_ * (L_ / 64), 512, 0, stream>>>(x, w1, b1, w2, b2, coef);
    k_sample<<<B_ * 64 * 12, 256, 0, stream>>>(x, coef, Sg);
    k_gemm<<<B_ * (L_ / 64), 512, 0, stream>>>(Wpk, bias, Sg, out);
}